// Round 4
// baseline (584.616 us; speedup 1.0000x reference)
//
#include <hip/hip_runtime.h>
#include <cstddef>
#include <cstdint>

#define NSEQ 2048
#define NB 2
#define NH 16
#define WINDOW 512

#define LOG2E 1.44269504088896f
#define QSCALE 0.180336877396f   // 0.125 * log2(e): folded into Q so softmax is base-2

typedef __attribute__((ext_vector_type(8))) short short8;          // bf16x8 MFMA operand
typedef __attribute__((ext_vector_type(4))) float f32x4;           // MFMA accumulator
typedef __attribute__((ext_vector_type(4))) unsigned short ushort4v;

// f32 -> bf16 RNE (bit trick; values are finite here)
__device__ __forceinline__ unsigned short f2bf(float f) {
    union { float f; unsigned u; } v; v.f = f;
    unsigned r = v.u + 0x7FFFu + ((v.u >> 16) & 1u);
    return (unsigned short)(r >> 16);
}

// pack 2 f32 -> 2 bf16 in one u32 (lo=a, hi=b)
__device__ __forceinline__ unsigned cvt_pk_bf16(float a, float b) {
    unsigned r;
    asm("v_cvt_pk_bf16_f32 %0, %1, %2" : "=v"(r) : "v"(a), "v"(b));
    return r;
}

// async global->LDS, 16B per lane (dest = wave-uniform base + lane*16)
typedef const __attribute__((address_space(1))) unsigned int* gasp;
typedef __attribute__((address_space(3))) unsigned int* lasp;
__device__ __forceinline__ void gll16(const void* g, void* l) {
    __builtin_amdgcn_global_load_lds((gasp)g, (lasp)l, 16, 0, 0);
}

__device__ __forceinline__ f32x4 mfma16(short8 a, short8 b, f32x4 c) {
    return __builtin_amdgcn_mfma_f32_16x16x32_bf16(a, b, c, 0, 0, 0);
}

// ---------------------------------------------------------------------------
// merged f32 -> bf16 cast for both activations (4 elems/thread)
// ---------------------------------------------------------------------------
__global__ __launch_bounds__(256)
void castk2(const float* __restrict__ a, const float* __restrict__ b,
            unsigned short* __restrict__ oa, unsigned short* __restrict__ ob) {
    int i = blockIdx.x * 256 + threadIdx.x;      // 0 .. 2*1048576-1
    const float* src = a; unsigned short* dst = oa;
    if (i >= 1048576) { src = b; dst = ob; i -= 1048576; }
    float4 v = ((const float4*)src)[i];
    ushort4v o;
    o[0] = f2bf(v.x); o[1] = f2bf(v.y); o[2] = f2bf(v.z); o[3] = f2bf(v.w);
    ((ushort4v*)dst)[i] = o;
}

// ---------------------------------------------------------------------------
// all six W[K=1024][N] f32 -> Wt[N][K] bf16 transposes in one launch
// ---------------------------------------------------------------------------
__global__ __launch_bounds__(256)
void wtrans_all(const float* __restrict__ Wq, const float* __restrict__ Wk1,
                const float* __restrict__ Wv1, const float* __restrict__ Wk2,
                const float* __restrict__ Wv2, const float* __restrict__ Wout,
                unsigned short* __restrict__ Wqt, unsigned short* __restrict__ Wk1t,
                unsigned short* __restrict__ Wv1t, unsigned short* __restrict__ Wk2t,
                unsigned short* __restrict__ Wv2t, unsigned short* __restrict__ Wot)
{
    __shared__ float tile[32][33];
    int id = blockIdx.x;
    const float* S; unsigned short* D; int N;
    if (id < 1024)      { S = Wq;   D = Wqt;  N = 1024; }
    else if (id < 2048) { S = Wk1;  D = Wk1t; N = 1024; id -= 1024; }
    else if (id < 4096) { S = Wv1;  D = Wv1t; N = 2048; id -= 2048; }
    else if (id < 6144) { S = Wk2;  D = Wk2t; N = 2048; id -= 4096; }
    else if (id < 7168) { S = Wv2;  D = Wv2t; N = 1024; id -= 6144; }
    else                { S = Wout; D = Wot;  N = 1024; id -= 7168; }
    const int nt = N >> 5;
    const int n0 = (id & (nt - 1)) << 5;
    const int k0 = (id / nt) << 5;
    const int tx = threadIdx.x & 31, ty = threadIdx.x >> 5;   // 32 x 8
#pragma unroll
    for (int i = 0; i < 4; ++i)
        tile[ty + i * 8][tx] = S[(size_t)(k0 + ty + i * 8) * N + n0 + tx];
    __syncthreads();
#pragma unroll
    for (int i = 0; i < 4; ++i)
        D[(size_t)(n0 + ty + i * 8) * 1024 + k0 + tx] = f2bf(tile[tx][ty + i * 8]);
}

// ---------------------------------------------------------------------------
// merged projection GEMM: [4096 x 7168 x 1024], m97 structure.
// columns [0,1024): Qp (A=Xq, scaled by QSCALE)   [1024,2048): K1
// [2048,4096): V1 per-head transposed             [4096,6144): K2
// [6144,7168): V2 per-head transposed.  Bt = merged [7168][1024].
// ---------------------------------------------------------------------------
__global__ __launch_bounds__(256)
void gemm_proj(const unsigned short* __restrict__ Aq, const unsigned short* __restrict__ Akv,
               const unsigned short* __restrict__ Bt,
               unsigned short* __restrict__ Qp,
               unsigned short* __restrict__ K1p, unsigned short* __restrict__ V1t,
               unsigned short* __restrict__ K2p, unsigned short* __restrict__ V2t)
{
    constexpr int K = 1024;
    __shared__ __align__(16) unsigned short As[128 * 32];
    __shared__ __align__(16) unsigned short Bs[128 * 32];
    const int t = threadIdx.x;
    const int l = t & 63, w = t >> 6;
    const int q = l & 15, g = l >> 4;
    const int bm = blockIdx.y * 128, bn = blockIdx.x * 128;
    const int wm = (w & 1) * 64, wn = (w >> 1) * 64;

    f32x4 acc[4][4];
    const f32x4 zero = {0.f, 0.f, 0.f, 0.f};
#pragma unroll
    for (int i = 0; i < 4; ++i)
#pragma unroll
        for (int j = 0; j < 4; ++j) acc[i][j] = zero;

    const unsigned short* Abase = ((bn < 1024) ? Aq : Akv) + (size_t)bm * K;
    const unsigned short* Bbase = Bt + (size_t)bn * K;

    for (int k0 = 0; k0 < K; k0 += 32) {
        __syncthreads();
#pragma unroll
        for (int it = 0; it < 2; ++it) {
            int c = w * 128 + it * 64 + l;
            int r = c >> 2, sg = c & 3;
            gll16(Abase + (size_t)r * K + k0 + sg * 8, (char*)As + c * 16);
            gll16(Bbase + (size_t)r * K + k0 + sg * 8, (char*)Bs + c * 16);
        }
        __syncthreads();
        short8 a[4], b[4];
#pragma unroll
        for (int ms = 0; ms < 4; ++ms)
            a[ms] = *(const short8*)(As + (wm + ms * 16 + q) * 32 + g * 8);
#pragma unroll
        for (int ns = 0; ns < 4; ++ns)
            b[ns] = *(const short8*)(Bs + (wn + ns * 16 + q) * 32 + g * 8);
#pragma unroll
        for (int ms = 0; ms < 4; ++ms)
#pragma unroll
            for (int ns = 0; ns < 4; ++ns)
                acc[ms][ns] = mfma16(a[ms], b[ns], acc[ms][ns]);
    }

    const int colbase = bn + wn;   // 64-aligned, range uniform per wave-half
    if (colbase < 1024) {          // Qp (pre-scaled)
#pragma unroll
        for (int ms = 0; ms < 4; ++ms)
#pragma unroll
            for (int r = 0; r < 4; ++r) {
                int row = bm + wm + ms * 16 + g * 4 + r;
                unsigned short* crow = Qp + (size_t)row * 1024 + colbase;
#pragma unroll
                for (int ns = 0; ns < 4; ++ns) crow[ns * 16 + q] = f2bf(acc[ms][ns][r] * QSCALE);
            }
    } else if (colbase < 2048) {   // K1 [4096][1024]
#pragma unroll
        for (int ms = 0; ms < 4; ++ms)
#pragma unroll
            for (int r = 0; r < 4; ++r) {
                int row = bm + wm + ms * 16 + g * 4 + r;
                unsigned short* crow = K1p + (size_t)row * 1024 + colbase - 1024;
#pragma unroll
                for (int ns = 0; ns < 4; ++ns) crow[ns * 16 + q] = f2bf(acc[ms][ns][r]);
            }
    } else if (colbase < 4096) {   // V1 per-head transposed, DVH=128
#pragma unroll
        for (int ms = 0; ms < 4; ++ms) {
            int row0 = bm + wm + ms * 16 + g * 4;
            int bb = row0 >> 11, nn = row0 & 2047;
#pragma unroll
            for (int ns = 0; ns < 4; ++ns) {
                int c2 = colbase - 2048 + ns * 16 + q;
                int h = c2 >> 7, d = c2 & 127;
                ushort4v pk;
#pragma unroll
                for (int r = 0; r < 4; ++r) pk[r] = f2bf(acc[ms][ns][r]);
                *(ushort4v*)(V1t + ((size_t)((bb * NH + h) * 128 + d)) * NSEQ + nn) = pk;
            }
        }
    } else if (colbase < 6144) {   // K2 [4096][2048]
#pragma unroll
        for (int ms = 0; ms < 4; ++ms)
#pragma unroll
            for (int r = 0; r < 4; ++r) {
                int row = bm + wm + ms * 16 + g * 4 + r;
                unsigned short* crow = K2p + (size_t)row * 2048 + colbase - 4096;
#pragma unroll
                for (int ns = 0; ns < 4; ++ns) crow[ns * 16 + q] = f2bf(acc[ms][ns][r]);
            }
    } else {                       // V2 per-head transposed, DVH=64
#pragma unroll
        for (int ms = 0; ms < 4; ++ms) {
            int row0 = bm + wm + ms * 16 + g * 4;
            int bb = row0 >> 11, nn = row0 & 2047;
#pragma unroll
            for (int ns = 0; ns < 4; ++ns) {
                int c2 = colbase - 6144 + ns * 16 + q;
                int h = c2 >> 6, d = c2 & 63;
                ushort4v pk;
#pragma unroll
                for (int r = 0; r < 4; ++r) pk[r] = f2bf(acc[ms][ns][r]);
                *(ushort4v*)(V2t + ((size_t)((bb * NH + h) * 64 + d)) * NSEQ + nn) = pk;
            }
        }
    }
}

// ---------------------------------------------------------------------------
// final projection: out[4096][1024] f32 = AO[4096][1024] @ Wot^T
// ---------------------------------------------------------------------------
__global__ __launch_bounds__(256)
void gemm_out(const unsigned short* __restrict__ A, const unsigned short* __restrict__ Bt,
              float* __restrict__ C)
{
    constexpr int K = 1024;
    __shared__ __align__(16) unsigned short As[128 * 32];
    __shared__ __align__(16) unsigned short Bs[128 * 32];
    const int t = threadIdx.x;
    const int l = t & 63, w = t >> 6;
    const int q = l & 15, g = l >> 4;
    const int bm = blockIdx.y * 128, bn = blockIdx.x * 128;
    const int wm = (w & 1) * 64, wn = (w >> 1) * 64;

    f32x4 acc[4][4];
    const f32x4 zero = {0.f, 0.f, 0.f, 0.f};
#pragma unroll
    for (int i = 0; i < 4; ++i)
#pragma unroll
        for (int j = 0; j < 4; ++j) acc[i][j] = zero;

    const unsigned short* Abase = A + (size_t)bm * K;
    const unsigned short* Bbase = Bt + (size_t)bn * K;

    for (int k0 = 0; k0 < K; k0 += 32) {
        __syncthreads();
#pragma unroll
        for (int it = 0; it < 2; ++it) {
            int c = w * 128 + it * 64 + l;
            int r = c >> 2, sg = c & 3;
            gll16(Abase + (size_t)r * K + k0 + sg * 8, (char*)As + c * 16);
            gll16(Bbase + (size_t)r * K + k0 + sg * 8, (char*)Bs + c * 16);
        }
        __syncthreads();
        short8 a[4], b[4];
#pragma unroll
        for (int ms = 0; ms < 4; ++ms)
            a[ms] = *(const short8*)(As + (wm + ms * 16 + q) * 32 + g * 8);
#pragma unroll
        for (int ns = 0; ns < 4; ++ns)
            b[ns] = *(const short8*)(Bs + (wn + ns * 16 + q) * 32 + g * 8);
#pragma unroll
        for (int ms = 0; ms < 4; ++ms)
#pragma unroll
            for (int ns = 0; ns < 4; ++ns)
                acc[ms][ns] = mfma16(a[ms], b[ns], acc[ms][ns]);
    }

#pragma unroll
    for (int ms = 0; ms < 4; ++ms)
#pragma unroll
        for (int r = 0; r < 4; ++r) {
            int row = bm + wm + ms * 16 + g * 4 + r;
            float* crow = C + (size_t)row * 1024 + bn + wn;
#pragma unroll
            for (int ns = 0; ns < 4; ++ns) crow[ns * 16 + q] = acc[ms][ns][r];
        }
}

// ---------------------------------------------------------------------------
// MFMA flash attend, 2-phase K prefetch + V direct-to-register.
// Q pre-scaled by 0.125*log2e -> base-2 softmax; sink as m0, l0=1.
// Two mask-free loop segments: j0 <= i0 and j0 >= i0+WINDOW; masks only on
// the two wave-uniform edge tiles. T13 defer-rescale (THR=8 log2 units).
// ---------------------------------------------------------------------------
template <int DK, int DV, bool SILU, bool Q_PH, bool O_PH>
__global__ __launch_bounds__(256)
void attend_mfma(const unsigned short* __restrict__ Qg,
                 const unsigned short* __restrict__ Kg,
                 const unsigned short* __restrict__ Vtg,
                 const float* __restrict__ sink,
                 unsigned short* __restrict__ Og)
{
    constexpr int NS = DV / 16;           // PV n-subtiles
    constexpr int NDB = DK / 32;          // QK k-blocks
    constexpr int KROWB = DK * 2;         // K LDS row bytes
    constexpr int KSEGS = KROWB / 16;
    constexpr int KBUF = 64 * KROWB;      // one K buffer (8/16 KB)
    constexpr int NCH = (64 * KSEGS) / 256;  // gll16 per thread per tile
    constexpr int KSTRIDE = NH * DK;      // K global row stride (elems)

    __shared__ __align__(16) char KsB[2 * KBUF];
    __shared__ __align__(16) char PsB[64 * 128];

    const int t = threadIdx.x, l = t & 63, w = t >> 6;
    const int q = l & 15, g = l >> 4;
    const int bh = blockIdx.x, bi = bh >> 4, h = bh & 15;
    const int i0 = blockIdx.y * 64;
    const int iq = i0 + w * 16 + q;
    const int qrow = w * 16 + q;

    // Q fragment (registers for whole kernel)
    const unsigned short* qbase;
    if constexpr (Q_PH)
        qbase = Qg + ((size_t)((bi * NH + h) * NSEQ + iq)) * DK;
    else
        qbase = Qg + ((size_t)(bi * NSEQ + iq)) * (NH * DK) + h * DK;
    short8 qf[NDB];
#pragma unroll
    for (int db = 0; db < NDB; ++db)
        qf[db] = *(const short8*)(qbase + db * 32 + g * 8);

    // K staging lane constants (hoisted; per tile only +j0*KSTRIDE)
    const unsigned short* kbase = Kg + (size_t)(bi * NSEQ) * KSTRIDE + h * DK;
    const unsigned short* ksrc[NCH];
    int kdst[NCH];
#pragma unroll
    for (int it = 0; it < NCH; ++it) {
        int c = w * (NCH * 64) + it * 64 + l;
        int kv = c / KSEGS, sg = (c % KSEGS) ^ (kv & 7);
        ksrc[it] = kbase + kv * KSTRIDE + sg * 8;
        kdst[it] = c * 16;
    }
    // K fragment read offsets (kvr&7 == q&7, s-part is a compile-time imm)
    int kro[NDB];
#pragma unroll
    for (int db = 0; db < NDB; ++db)
        kro[db] = q * KROWB + (((db * 4 + g) ^ (q & 7)) << 4);
    // P LDS offsets
    int pw[4], pr[2];
#pragma unroll
    for (int s = 0; s < 4; ++s) pw[s] = qrow * 128 + ((s * 32 + g * 8) ^ ((q & 7) << 4));
#pragma unroll
    for (int kb = 0; kb < 2; ++kb) pr[kb] = qrow * 128 + (((kb * 4 + g) ^ (q & 7)) << 4);
    // V lane pointers (per-head transposed V: [d][n])
    const unsigned short* vbase = Vtg + (size_t)((bi * NH + h) * DV) * NSEQ;
    const unsigned short* vp[NS];
#pragma unroll
    for (int ns = 0; ns < NS; ++ns) vp[ns] = vbase + (ns * 16 + q) * NSEQ + g * 8;

    float m = sink[h] * LOG2E, lsum = 1.0f;
    f32x4 o[NS];
    const f32x4 zero = {0.f, 0.f, 0.f, 0.f};
#pragma unroll
    for (int ns = 0; ns < NS; ++ns) o[ns] = zero;

    // active tiles: segment A j0 = 0..i0 (last = diagonal), segment B j0 = i0+512.. (first = window edge)
    const int nA = (i0 >> 6) + 1;
    const int jB = i0 + WINDOW;
    const int nB = (jB < NSEQ) ? ((NSEQ - jB) >> 6) : 0;
    const int ntot = nA + nB;

    auto J0 = [&](int tt) { return (tt < nA) ? (tt << 6) : (jB + ((tt - nA) << 6)); };
    auto stageK = [&](int j0n, int bb) {
#pragma unroll
        for (int it = 0; it < NCH; ++it)
            gll16(ksrc[it] + (size_t)j0n * KSTRIDE, KsB + bb * KBUF + kdst[it]);
    };

    stageK(0, 0);
    int buf = 0;

    for (int tt = 0; tt < ntot; ++tt) {
        const int j0 = J0(tt);
        __syncthreads();              // buf's stage complete; prev tile's LDS reads done

        // V tile -> registers (issued first: oldest vmcnt entries, waited at PV)
        short8 vf[NS][2];
#pragma unroll
        for (int ns = 0; ns < NS; ++ns) {
            const unsigned short* vpt = vp[ns] + j0;
            vf[ns][0] = *(const short8*)vpt;
            vf[ns][1] = *(const short8*)(vpt + 32);
        }
        // prefetch next K tile into the other buffer (in flight through this tile)
        if (tt + 1 < ntot) stageK(J0(tt + 1), buf ^ 1);

        // QK^T: st[s][r] = S[kv = s*16+g*4+r][q]
        const int bo = buf * KBUF;
        float st[4][4];
#pragma unroll
        for (int s = 0; s < 4; ++s) {
            f32x4 sacc = zero;
#pragma unroll
            for (int db = 0; db < NDB; ++db) {
                short8 kf = *(const short8*)(KsB + bo + s * (16 * KROWB) + kro[db]);
                sacc = mfma16(kf, qf[db], sacc);
            }
#pragma unroll
            for (int r = 0; r < 4; ++r) st[s][r] = sacc[r];
        }

        // band mask only on the two edge tiles (wave-uniform condition)
        if (j0 == i0 || j0 == jB) {
#pragma unroll
            for (int s = 0; s < 4; ++s)
#pragma unroll
                for (int r = 0; r < 4; ++r) {
                    int j = j0 + s * 16 + g * 4 + r;
                    if (j > iq && (j - iq) <= WINDOW) st[s][r] = -3.0e38f;
                }
        }

        float mx = st[0][0];
#pragma unroll
        for (int s = 0; s < 4; ++s)
#pragma unroll
            for (int r = 0; r < 4; ++r)
                if (s || r) mx = fmaxf(mx, st[s][r]);
        mx = fmaxf(mx, __shfl_xor(mx, 16));
        mx = fmaxf(mx, __shfl_xor(mx, 32));

        if (!__all(mx - m <= 8.0f)) {      // T13 defer-rescale
            const float nm = fmaxf(m, mx);
            const float corr = exp2f(m - nm);
            m = nm;
            lsum *= corr;
            float cr[4];
#pragma unroll
            for (int r = 0; r < 4; ++r) cr[r] = __shfl(corr, g * 4 + r);
#pragma unroll
            for (int ns = 0; ns < NS; ++ns)
#pragma unroll
                for (int r = 0; r < 4; ++r) o[ns][r] *= cr[r];
        }

        float ps = 0.f;
#pragma unroll
        for (int s = 0; s < 4; ++s) {
            float p0 = exp2f(st[s][0] - m);
            float p1 = exp2f(st[s][1] - m);
            float p2 = exp2f(st[s][2] - m);
            float p3 = exp2f(st[s][3] - m);
            ps += (p0 + p1) + (p2 + p3);
            uint2 pk;
            pk.x = cvt_pk_bf16(p0, p1);
            pk.y = cvt_pk_bf16(p2, p3);
            *(uint2*)(PsB + pw[s]) = pk;
        }
        ps += __shfl_xor(ps, 16);
        ps += __shfl_xor(ps, 32);
        lsum += ps;

        // PV (P rows are wave-private; no barrier needed)
#pragma unroll
        for (int kb = 0; kb < 2; ++kb) {
            short8 pf = *(const short8*)(PsB + pr[kb]);
#pragma unroll
            for (int ns = 0; ns < NS; ++ns)
                o[ns] = mfma16(pf, vf[ns][kb], o[ns]);
        }
        buf ^= 1;
    }

    // epilogue: normalize (+silu), write bf16
    const float inv = 1.0f / lsum;
    float ivr[4];
#pragma unroll
    for (int r = 0; r < 4; ++r) ivr[r] = __shfl(inv, g * 4 + r);
#pragma unroll
    for (int ns = 0; ns < NS; ++ns)
#pragma unroll
        for (int r = 0; r < 4; ++r) {
            float x = o[ns][r] * ivr[r];
            if constexpr (SILU) x = x / (1.0f + __expf(-x)) * QSCALE;
            int qr = i0 + w * 16 + g * 4 + r;
            int d = ns * 16 + q;
            size_t off;
            if constexpr (O_PH)
                off = ((size_t)((bi * NH + h) * NSEQ + qr)) * DV + d;
            else
                off = ((size_t)(bi * NSEQ + qr)) * (NH * DV) + h * DV + d;
            Og[off] = f2bf(x);
        }
}

// ---------------------------------------------------------------------------
extern "C" void kernel_launch(void* const* d_in, const int* in_sizes, int n_in,
                              void* d_out, int out_size, void* d_ws, size_t ws_size,
                              hipStream_t stream)
{
    (void)in_sizes; (void)n_in; (void)out_size; (void)ws_size;
    const float* queries = (const float*)d_in[0];
    const float* kvin    = (const float*)d_in[1];
    const float* Wq      = (const float*)d_in[2];
    const float* Wk1     = (const float*)d_in[3];
    const float* Wv1     = (const float*)d_in[4];
    const float* Wk2     = (const float*)d_in[5];
    const float* Wv2     = (const float*)d_in[6];
    const float* Wout    = (const float*)d_in[7];
    const float* sink    = (const float*)d_in[8];
    float* out = (float*)d_out;

    unsigned short* Xq   = (unsigned short*)d_ws;                   // [4096][1024]
    unsigned short* Xkv  = Xq   + (size_t)4096 * 1024;              // [4096][1024]
    unsigned short* Wqt  = Xkv  + (size_t)4096 * 1024;              // [7168][1024] merged Bt
    unsigned short* Wk1t = Wqt  + (size_t)1024 * 1024;
    unsigned short* Wv1t = Wk1t + (size_t)1024 * 1024;
    unsigned short* Wk2t = Wv1t + (size_t)2048 * 1024;
    unsigned short* Wv2t = Wk2t + (size_t)2048 * 1024;
    unsigned short* Wot  = Wv2t + (size_t)1024 * 1024;              // [1024][1024]
    unsigned short* Qp   = Wot  + (size_t)1024 * 1024;              // [4096][1024], pre-scaled
    unsigned short* K1p  = Qp   + (size_t)4096 * 1024;              // [4096][1024]
    unsigned short* V1t  = K1p  + (size_t)4096 * 1024;              // [2*16*128][2048]
    unsigned short* K2p  = V1t  + (size_t)2 * 16 * 128 * 2048;      // [4096][2048]
    unsigned short* V2t  = K2p  + (size_t)4096 * 2048;              // [2*16*64][2048]
    unsigned short* Hb   = V2t  + (size_t)2 * 16 * 64 * 2048;       // [2*16*2048][128], pre-scaled
    unsigned short* AO   = Hb   + (size_t)2 * 16 * 2048 * 128;      // [4096][1024]

    dim3 blk(256);

    castk2<<<8192, blk, 0, stream>>>(queries, kvin, Xq, Xkv);
    wtrans_all<<<8192, blk, 0, stream>>>(Wq, Wk1, Wv1, Wk2, Wv2, Wout,
                                         Wqt, Wk1t, Wv1t, Wk2t, Wv2t, Wot);

    // merged Q|K1|V1|K2|V2 projection: 4096 x 7168 x 1024
    gemm_proj<<<dim3(56, 32), blk, 0, stream>>>(Xq, Xkv, Wqt, Qp, K1p, V1t, K2p, V2t);

    attend_mfma<64, 128, true, false, true><<<dim3(32, 32), blk, 0, stream>>>(
        Qp, K1p, V1t, sink, Hb);
    attend_mfma<128, 64, false, true, false><<<dim3(32, 32), blk, 0, stream>>>(
        Hb, K2p, V2t, sink, AO);

    gemm_out<<<dim3(8, 32), blk, 0, stream>>>(AO, Wot, out);
}

// Round 5
// 429.786 us; speedup vs baseline: 1.3602x; 1.3602x over previous
//
#include <hip/hip_runtime.h>
#include <cstddef>
#include <cstdint>

#define NSEQ 2048
#define NB 2
#define NH 16
#define WINDOW 512

#define LOG2E 1.44269504088896f
#define QSCALE 0.180336877396f   // 0.125 * log2(e): folded into Q so softmax is base-2

typedef __attribute__((ext_vector_type(8))) short short8;          // bf16x8 MFMA operand
typedef __attribute__((ext_vector_type(4))) float f32x4;           // MFMA accumulator
typedef __attribute__((ext_vector_type(4))) unsigned short ushort4v;

// f32 -> bf16 RNE (bit trick; values are finite here)
__device__ __forceinline__ unsigned short f2bf(float f) {
    union { float f; unsigned u; } v; v.f = f;
    unsigned r = v.u + 0x7FFFu + ((v.u >> 16) & 1u);
    return (unsigned short)(r >> 16);
}

// pack 2 f32 -> 2 bf16 in one u32 (lo=a, hi=b)
__device__ __forceinline__ unsigned cvt_pk_bf16(float a, float b) {
    unsigned r;
    asm("v_cvt_pk_bf16_f32 %0, %1, %2" : "=v"(r) : "v"(a), "v"(b));
    return r;
}

// async global->LDS, 16B per lane (dest = wave-uniform base + lane*16)
typedef const __attribute__((address_space(1))) unsigned int* gasp;
typedef __attribute__((address_space(3))) unsigned int* lasp;
__device__ __forceinline__ void gll16(const void* g, void* l) {
    __builtin_amdgcn_global_load_lds((gasp)g, (lasp)l, 16, 0, 0);
}

__device__ __forceinline__ f32x4 mfma16(short8 a, short8 b, f32x4 c) {
    return __builtin_amdgcn_mfma_f32_16x16x32_bf16(a, b, c, 0, 0, 0);
}

// ---------------------------------------------------------------------------
// merged f32 -> bf16 cast for both activations (4 elems/thread)
// ---------------------------------------------------------------------------
__global__ __launch_bounds__(256)
void castk2(const float* __restrict__ a, const float* __restrict__ b,
            unsigned short* __restrict__ oa, unsigned short* __restrict__ ob) {
    int i = blockIdx.x * 256 + threadIdx.x;      // 0 .. 2*1048576-1
    const float* src = a; unsigned short* dst = oa;
    if (i >= 1048576) { src = b; dst = ob; i -= 1048576; }
    float4 v = ((const float4*)src)[i];
    ushort4v o;
    o[0] = f2bf(v.x); o[1] = f2bf(v.y); o[2] = f2bf(v.z); o[3] = f2bf(v.w);
    ((ushort4v*)dst)[i] = o;
}

// ---------------------------------------------------------------------------
// all six W[K=1024][N] f32 -> Wt[N][K] bf16 transposes in one launch
// ---------------------------------------------------------------------------
__global__ __launch_bounds__(256)
void wtrans_all(const float* __restrict__ Wq, const float* __restrict__ Wk1,
                const float* __restrict__ Wv1, const float* __restrict__ Wk2,
                const float* __restrict__ Wv2, const float* __restrict__ Wout,
                unsigned short* __restrict__ Wqt, unsigned short* __restrict__ Wk1t,
                unsigned short* __restrict__ Wv1t, unsigned short* __restrict__ Wk2t,
                unsigned short* __restrict__ Wv2t, unsigned short* __restrict__ Wot)
{
    __shared__ float tile[32][33];
    int id = blockIdx.x;
    const float* S; unsigned short* D; int N;
    if (id < 1024)      { S = Wq;   D = Wqt;  N = 1024; }
    else if (id < 2048) { S = Wk1;  D = Wk1t; N = 1024; id -= 1024; }
    else if (id < 4096) { S = Wv1;  D = Wv1t; N = 2048; id -= 2048; }
    else if (id < 6144) { S = Wk2;  D = Wk2t; N = 2048; id -= 4096; }
    else if (id < 7168) { S = Wv2;  D = Wv2t; N = 1024; id -= 6144; }
    else                { S = Wout; D = Wot;  N = 1024; id -= 7168; }
    const int nt = N >> 5;
    const int n0 = (id & (nt - 1)) << 5;
    const int k0 = (id / nt) << 5;
    const int tx = threadIdx.x & 31, ty = threadIdx.x >> 5;   // 32 x 8
#pragma unroll
    for (int i = 0; i < 4; ++i)
        tile[ty + i * 8][tx] = S[(size_t)(k0 + ty + i * 8) * N + n0 + tx];
    __syncthreads();
#pragma unroll
    for (int i = 0; i < 4; ++i)
        D[(size_t)(n0 + ty + i * 8) * 1024 + k0 + tx] = f2bf(tile[tx][ty + i * 8]);
}

// ---------------------------------------------------------------------------
// merged projection GEMM: [4096 x 7168 x 1024], m97 structure.
// columns [0,1024): Qp (A=Xq, scaled by QSCALE)   [1024,2048): K1
// [2048,4096): V1 per-head transposed             [4096,6144): K2
// [6144,7168): V2 per-head transposed.  Bt = merged [7168][1024].
// ---------------------------------------------------------------------------
__global__ __launch_bounds__(256)
void gemm_proj(const unsigned short* __restrict__ Aq, const unsigned short* __restrict__ Akv,
               const unsigned short* __restrict__ Bt,
               unsigned short* __restrict__ Qp,
               unsigned short* __restrict__ K1p, unsigned short* __restrict__ V1t,
               unsigned short* __restrict__ K2p, unsigned short* __restrict__ V2t)
{
    constexpr int K = 1024;
    __shared__ __align__(16) unsigned short As[128 * 32];
    __shared__ __align__(16) unsigned short Bs[128 * 32];
    const int t = threadIdx.x;
    const int l = t & 63, w = t >> 6;
    const int q = l & 15, g = l >> 4;
    const int bm = blockIdx.y * 128, bn = blockIdx.x * 128;
    const int wm = (w & 1) * 64, wn = (w >> 1) * 64;

    f32x4 acc[4][4];
    const f32x4 zero = {0.f, 0.f, 0.f, 0.f};
#pragma unroll
    for (int i = 0; i < 4; ++i)
#pragma unroll
        for (int j = 0; j < 4; ++j) acc[i][j] = zero;

    const unsigned short* Abase = ((bn < 1024) ? Aq : Akv) + (size_t)bm * K;
    const unsigned short* Bbase = Bt + (size_t)bn * K;

    for (int k0 = 0; k0 < K; k0 += 32) {
        __syncthreads();
#pragma unroll
        for (int it = 0; it < 2; ++it) {
            int c = w * 128 + it * 64 + l;
            int r = c >> 2, sg = c & 3;
            gll16(Abase + (size_t)r * K + k0 + sg * 8, (char*)As + c * 16);
            gll16(Bbase + (size_t)r * K + k0 + sg * 8, (char*)Bs + c * 16);
        }
        __syncthreads();
        short8 a[4], b[4];
#pragma unroll
        for (int ms = 0; ms < 4; ++ms)
            a[ms] = *(const short8*)(As + (wm + ms * 16 + q) * 32 + g * 8);
#pragma unroll
        for (int ns = 0; ns < 4; ++ns)
            b[ns] = *(const short8*)(Bs + (wn + ns * 16 + q) * 32 + g * 8);
#pragma unroll
        for (int ms = 0; ms < 4; ++ms)
#pragma unroll
            for (int ns = 0; ns < 4; ++ns)
                acc[ms][ns] = mfma16(a[ms], b[ns], acc[ms][ns]);
    }

    const int colbase = bn + wn;   // 64-aligned, range uniform per wave-half
    if (colbase < 1024) {          // Qp (pre-scaled)
#pragma unroll
        for (int ms = 0; ms < 4; ++ms)
#pragma unroll
            for (int r = 0; r < 4; ++r) {
                int row = bm + wm + ms * 16 + g * 4 + r;
                unsigned short* crow = Qp + (size_t)row * 1024 + colbase;
#pragma unroll
                for (int ns = 0; ns < 4; ++ns) crow[ns * 16 + q] = f2bf(acc[ms][ns][r] * QSCALE);
            }
    } else if (colbase < 2048) {   // K1 [4096][1024]
#pragma unroll
        for (int ms = 0; ms < 4; ++ms)
#pragma unroll
            for (int r = 0; r < 4; ++r) {
                int row = bm + wm + ms * 16 + g * 4 + r;
                unsigned short* crow = K1p + (size_t)row * 1024 + colbase - 1024;
#pragma unroll
                for (int ns = 0; ns < 4; ++ns) crow[ns * 16 + q] = f2bf(acc[ms][ns][r]);
            }
    } else if (colbase < 4096) {   // V1 per-head transposed, DVH=128
#pragma unroll
        for (int ms = 0; ms < 4; ++ms) {
            int row0 = bm + wm + ms * 16 + g * 4;
            int bb = row0 >> 11, nn = row0 & 2047;
#pragma unroll
            for (int ns = 0; ns < 4; ++ns) {
                int c2 = colbase - 2048 + ns * 16 + q;
                int h = c2 >> 7, d = c2 & 127;
                ushort4v pk;
#pragma unroll
                for (int r = 0; r < 4; ++r) pk[r] = f2bf(acc[ms][ns][r]);
                *(ushort4v*)(V1t + ((size_t)((bb * NH + h) * 128 + d)) * NSEQ + nn) = pk;
            }
        }
    } else if (colbase < 6144) {   // K2 [4096][2048]
#pragma unroll
        for (int ms = 0; ms < 4; ++ms)
#pragma unroll
            for (int r = 0; r < 4; ++r) {
                int row = bm + wm + ms * 16 + g * 4 + r;
                unsigned short* crow = K2p + (size_t)row * 2048 + colbase - 4096;
#pragma unroll
                for (int ns = 0; ns < 4; ++ns) crow[ns * 16 + q] = f2bf(acc[ms][ns][r]);
            }
    } else {                       // V2 per-head transposed, DVH=64
#pragma unroll
        for (int ms = 0; ms < 4; ++ms) {
            int row0 = bm + wm + ms * 16 + g * 4;
            int bb = row0 >> 11, nn = row0 & 2047;
#pragma unroll
            for (int ns = 0; ns < 4; ++ns) {
                int c2 = colbase - 6144 + ns * 16 + q;
                int h = c2 >> 6, d = c2 & 63;
                ushort4v pk;
#pragma unroll
                for (int r = 0; r < 4; ++r) pk[r] = f2bf(acc[ms][ns][r]);
                *(ushort4v*)(V2t + ((size_t)((bb * NH + h) * 64 + d)) * NSEQ + nn) = pk;
            }
        }
    }
}

// ---------------------------------------------------------------------------
// final projection: out[4096][1024] f32 = AO[4096][1024] @ Wot^T
// ---------------------------------------------------------------------------
__global__ __launch_bounds__(256)
void gemm_out(const unsigned short* __restrict__ A, const unsigned short* __restrict__ Bt,
              float* __restrict__ C)
{
    constexpr int K = 1024;
    __shared__ __align__(16) unsigned short As[128 * 32];
    __shared__ __align__(16) unsigned short Bs[128 * 32];
    const int t = threadIdx.x;
    const int l = t & 63, w = t >> 6;
    const int q = l & 15, g = l >> 4;
    const int bm = blockIdx.y * 128, bn = blockIdx.x * 128;
    const int wm = (w & 1) * 64, wn = (w >> 1) * 64;

    f32x4 acc[4][4];
    const f32x4 zero = {0.f, 0.f, 0.f, 0.f};
#pragma unroll
    for (int i = 0; i < 4; ++i)
#pragma unroll
        for (int j = 0; j < 4; ++j) acc[i][j] = zero;

    const unsigned short* Abase = A + (size_t)bm * K;
    const unsigned short* Bbase = Bt + (size_t)bn * K;

    for (int k0 = 0; k0 < K; k0 += 32) {
        __syncthreads();
#pragma unroll
        for (int it = 0; it < 2; ++it) {
            int c = w * 128 + it * 64 + l;
            int r = c >> 2, sg = c & 3;
            gll16(Abase + (size_t)r * K + k0 + sg * 8, (char*)As + c * 16);
            gll16(Bbase + (size_t)r * K + k0 + sg * 8, (char*)Bs + c * 16);
        }
        __syncthreads();
        short8 a[4], b[4];
#pragma unroll
        for (int ms = 0; ms < 4; ++ms)
            a[ms] = *(const short8*)(As + (wm + ms * 16 + q) * 32 + g * 8);
#pragma unroll
        for (int ns = 0; ns < 4; ++ns)
            b[ns] = *(const short8*)(Bs + (wn + ns * 16 + q) * 32 + g * 8);
#pragma unroll
        for (int ms = 0; ms < 4; ++ms)
#pragma unroll
            for (int ns = 0; ns < 4; ++ns)
                acc[ms][ns] = mfma16(a[ms], b[ns], acc[ms][ns]);
    }

#pragma unroll
    for (int ms = 0; ms < 4; ++ms)
#pragma unroll
        for (int r = 0; r < 4; ++r) {
            int row = bm + wm + ms * 16 + g * 4 + r;
            float* crow = C + (size_t)row * 1024 + bn + wn;
#pragma unroll
            for (int ns = 0; ns < 4; ++ns) crow[ns * 16 + q] = acc[ms][ns][r];
        }
}

// ---------------------------------------------------------------------------
// MFMA flash attend. K AND V double-buffered in LDS via global_load_lds with
// next-tile prefetch issued right after the per-tile barrier (fire-and-forget;
// drained by the NEXT barrier after a full tile of compute cover).
// Q pre-scaled by 0.125*log2e -> base-2 softmax; sink as m0, l0=1.
// Mask applied only on the two wave-uniform edge tiles. T13 defer-rescale.
// ---------------------------------------------------------------------------
template <int DK, int DV, bool SILU, bool Q_PH, bool O_PH>
__global__ __launch_bounds__(256)
void attend_mfma(const unsigned short* __restrict__ Qg,
                 const unsigned short* __restrict__ Kg,
                 const unsigned short* __restrict__ Vtg,
                 const float* __restrict__ sink,
                 unsigned short* __restrict__ Og)
{
    constexpr int NS = DV / 16;           // PV n-subtiles
    constexpr int NDB = DK / 32;          // QK k-blocks
    constexpr int KROWB = DK * 2;         // K LDS row bytes
    constexpr int KSEGS = KROWB / 16;
    constexpr int KBUF = 64 * KROWB;      // one K buffer (8/16 KB)
    constexpr int VBUF = DV * 128;        // one V buffer (16/8 KB)
    constexpr int NCHK = (64 * KSEGS) / 256;
    constexpr int NCHV = (DV * 8) / 256;
    constexpr int KSTRIDE = NH * DK;      // K global row stride (elems)

    __shared__ __align__(16) char KsB[2 * KBUF];
    __shared__ __align__(16) char VsB[2 * VBUF];
    __shared__ __align__(16) char PsB[64 * 128];

    const int t = threadIdx.x, l = t & 63, w = t >> 6;
    const int q = l & 15, g = l >> 4;
    const int bh = blockIdx.x, bi = bh >> 4, h = bh & 15;
    const int i0 = blockIdx.y * 64;
    const int iq = i0 + w * 16 + q;
    const int qrow = w * 16 + q;

    // Q fragment (registers for whole kernel)
    const unsigned short* qbase;
    if constexpr (Q_PH)
        qbase = Qg + ((size_t)((bi * NH + h) * NSEQ + iq)) * DK;
    else
        qbase = Qg + ((size_t)(bi * NSEQ + iq)) * (NH * DK) + h * DK;
    short8 qf[NDB];
#pragma unroll
    for (int db = 0; db < NDB; ++db)
        qf[db] = *(const short8*)(qbase + db * 32 + g * 8);

    // K staging lane constants (per tile add j0*KSTRIDE)
    const unsigned short* kbase = Kg + (size_t)(bi * NSEQ) * KSTRIDE + h * DK;
    const unsigned short* ksrc[NCHK];
    int kdst[NCHK];
#pragma unroll
    for (int it = 0; it < NCHK; ++it) {
        int c = w * (NCHK * 64) + it * 64 + l;
        int kv = c / KSEGS, sg = (c % KSEGS) ^ (kv & 7);
        ksrc[it] = kbase + kv * KSTRIDE + sg * 8;
        kdst[it] = c * 16;
    }
    // V staging lane constants (per tile add j0)
    const unsigned short* vbase = Vtg + (size_t)((bi * NH + h) * DV) * NSEQ;
    const unsigned short* vsrc[NCHV];
    int vdst[NCHV];
#pragma unroll
    for (int it = 0; it < NCHV; ++it) {
        int c = w * (NCHV * 64) + it * 64 + l;
        int d = c >> 3, sg = (c & 7) ^ (d & 7);
        vsrc[it] = vbase + (size_t)d * NSEQ + sg * 8;
        vdst[it] = c * 16;
    }

    // fragment read offsets ((s*16+q)&7 == q&7, (ns*16+q)&7 == q&7)
    int kro[NDB];
#pragma unroll
    for (int db = 0; db < NDB; ++db)
        kro[db] = q * KROWB + (((db * 4 + g) ^ (q & 7)) << 4);
    int vro[2];
#pragma unroll
    for (int kb = 0; kb < 2; ++kb)
        vro[kb] = q * 128 + (((kb * 4 + g) ^ (q & 7)) << 4);
    int pw[4], pr[2];
#pragma unroll
    for (int s = 0; s < 4; ++s) pw[s] = qrow * 128 + ((s * 32 + g * 8) ^ ((q & 7) << 4));
#pragma unroll
    for (int kb = 0; kb < 2; ++kb) pr[kb] = qrow * 128 + (((kb * 4 + g) ^ (q & 7)) << 4);

    float m = sink[h] * LOG2E, lsum = 1.0f;
    f32x4 o[NS];
    const f32x4 zero = {0.f, 0.f, 0.f, 0.f};
#pragma unroll
    for (int ns = 0; ns < NS; ++ns) o[ns] = zero;

    // active tiles: segment A j0 = 0..i0 (last = diagonal), segment B j0 = i0+512..
    const int nA = (i0 >> 6) + 1;
    const int jB = i0 + WINDOW;
    const int nB = (jB < NSEQ) ? ((NSEQ - jB) >> 6) : 0;
    const int ntot = nA + nB;

    auto J0 = [&](int tt) { return (tt < nA) ? (tt << 6) : (jB + ((tt - nA) << 6)); };
    auto stage = [&](int j0n, int bb) {
#pragma unroll
        for (int it = 0; it < NCHK; ++it)
            gll16(ksrc[it] + (size_t)j0n * KSTRIDE, KsB + bb * KBUF + kdst[it]);
#pragma unroll
        for (int it = 0; it < NCHV; ++it)
            gll16(vsrc[it] + j0n, VsB + bb * VBUF + vdst[it]);
    };

    stage(0, 0);
    int buf = 0;

    for (int tt = 0; tt < ntot; ++tt) {
        const int j0 = J0(tt);
        __syncthreads();              // buf's stage landed; prev tile's LDS reads done

        // prefetch next tile into the other buffer (in flight through this tile)
        if (tt + 1 < ntot) stage(J0(tt + 1), buf ^ 1);

        // QK^T: st[s][r] = S[kv = s*16+g*4+r][q]
        const int ko = buf * KBUF;
        float st[4][4];
        __builtin_amdgcn_s_setprio(1);
#pragma unroll
        for (int s = 0; s < 4; ++s) {
            f32x4 sacc = zero;
#pragma unroll
            for (int db = 0; db < NDB; ++db) {
                short8 kf = *(const short8*)(KsB + ko + s * (16 * KROWB) + kro[db]);
                sacc = mfma16(kf, qf[db], sacc);
            }
#pragma unroll
            for (int r = 0; r < 4; ++r) st[s][r] = sacc[r];
        }
        __builtin_amdgcn_s_setprio(0);

        // band mask only on the two edge tiles (wave-uniform condition)
        if (j0 == i0 || j0 == jB) {
#pragma unroll
            for (int s = 0; s < 4; ++s)
#pragma unroll
                for (int r = 0; r < 4; ++r) {
                    int j = j0 + s * 16 + g * 4 + r;
                    if (j > iq && (j - iq) <= WINDOW) st[s][r] = -3.0e38f;
                }
        }

        float mx = st[0][0];
#pragma unroll
        for (int s = 0; s < 4; ++s)
#pragma unroll
            for (int r = 0; r < 4; ++r)
                if (s || r) mx = fmaxf(mx, st[s][r]);
        mx = fmaxf(mx, __shfl_xor(mx, 16));
        mx = fmaxf(mx, __shfl_xor(mx, 32));

        if (!__all(mx - m <= 8.0f)) {      // T13 defer-rescale
            const float nm = fmaxf(m, mx);
            const float corr = exp2f(m - nm);
            m = nm;
            lsum *= corr;
            float cr[4];
#pragma unroll
            for (int r = 0; r < 4; ++r) cr[r] = __shfl(corr, g * 4 + r);
#pragma unroll
            for (int ns = 0; ns < NS; ++ns)
#pragma unroll
                for (int r = 0; r < 4; ++r) o[ns][r] *= cr[r];
        }

        float ps = 0.f;
#pragma unroll
        for (int s = 0; s < 4; ++s) {
            float p0 = exp2f(st[s][0] - m);
            float p1 = exp2f(st[s][1] - m);
            float p2 = exp2f(st[s][2] - m);
            float p3 = exp2f(st[s][3] - m);
            ps += (p0 + p1) + (p2 + p3);
            uint2 pk;
            pk.x = cvt_pk_bf16(p0, p1);
            pk.y = cvt_pk_bf16(p2, p3);
            *(uint2*)(PsB + pw[s]) = pk;
        }
        ps += __shfl_xor(ps, 16);
        ps += __shfl_xor(ps, 32);
        lsum += ps;

        // PV (P rows are wave-private; no barrier needed)
        const int vo = buf * VBUF;
        __builtin_amdgcn_s_setprio(1);
#pragma unroll
        for (int kb = 0; kb < 2; ++kb) {
            short8 pf = *(const short8*)(PsB + pr[kb]);
#pragma unroll
            for (int ns = 0; ns < NS; ++ns) {
                short8 vf = *(const short8*)(VsB + vo + ns * (16 * 128) + vro[kb]);
                o[ns] = mfma16(pf, vf, o[ns]);
            }
        }
        __builtin_amdgcn_s_setprio(0);
        buf ^= 1;
    }

    // epilogue: normalize (+silu), write bf16
    const float inv = 1.0f / lsum;
    float ivr[4];
#pragma unroll
    for (int r = 0; r < 4; ++r) ivr[r] = __shfl(inv, g * 4 + r);
#pragma unroll
    for (int ns = 0; ns < NS; ++ns)
#pragma unroll
        for (int r = 0; r < 4; ++r) {
            float x = o[ns][r] * ivr[r];
            if constexpr (SILU) x = x / (1.0f + __expf(-x)) * QSCALE;
            int qr = i0 + w * 16 + g * 4 + r;
            int d = ns * 16 + q;
            size_t off;
            if constexpr (O_PH)
                off = ((size_t)((bi * NH + h) * NSEQ + qr)) * DV + d;
            else
                off = ((size_t)(bi * NSEQ + qr)) * (NH * DV) + h * DV + d;
            Og[off] = f2bf(x);
        }
}

// ---------------------------------------------------------------------------
extern "C" void kernel_launch(void* const* d_in, const int* in_sizes, int n_in,
                              void* d_out, int out_size, void* d_ws, size_t ws_size,
                              hipStream_t stream)
{
    (void)in_sizes; (void)n_in; (void)out_size; (void)ws_size;
    const float* queries = (const float*)d_in[0];
    const float* kvin    = (const float*)d_in[1];
    const float* Wq      = (const float*)d_in[2];
    const float* Wk1     = (const float*)d_in[3];
    const float* Wv1     = (const float*)d_in[4];
    const float* Wk2     = (const float*)d_in[5];
    const float* Wv2     = (const float*)d_in[6];
    const float* Wout    = (const float*)d_in[7];
    const float* sink    = (const float*)d_in[8];
    float* out = (float*)d_out;

    unsigned short* Xq   = (unsigned short*)d_ws;                   // [4096][1024]
    unsigned short* Xkv  = Xq   + (size_t)4096 * 1024;              // [4096][1024]
    unsigned short* Wqt  = Xkv  + (size_t)4096 * 1024;              // [7168][1024] merged Bt
    unsigned short* Wk1t = Wqt  + (size_t)1024 * 1024;
    unsigned short* Wv1t = Wk1t + (size_t)1024 * 1024;
    unsigned short* Wk2t = Wv1t + (size_t)2048 * 1024;
    unsigned short* Wv2t = Wk2t + (size_t)2048 * 1024;
    unsigned short* Wot  = Wv2t + (size_t)1024 * 1024;              // [1024][1024]
    unsigned short* Qp   = Wot  + (size_t)1024 * 1024;              // [4096][1024], pre-scaled
    unsigned short* K1p  = Qp   + (size_t)4096 * 1024;              // [4096][1024]
    unsigned short* V1t  = K1p  + (size_t)4096 * 1024;              // [2*16*128][2048]
    unsigned short* K2p  = V1t  + (size_t)2 * 16 * 128 * 2048;      // [4096][2048]
    unsigned short* V2t  = K2p  + (size_t)4096 * 2048;              // [2*16*64][2048]
    unsigned short* Hb   = V2t  + (size_t)2 * 16 * 64 * 2048;       // [2*16*2048][128], pre-scaled
    unsigned short* AO   = Hb   + (size_t)2 * 16 * 2048 * 128;      // [4096][1024]

    dim3 blk(256);

    castk2<<<8192, blk, 0, stream>>>(queries, kvin, Xq, Xkv);
    wtrans_all<<<8192, blk, 0, stream>>>(Wq, Wk1, Wv1, Wk2, Wv2, Wout,
                                         Wqt, Wk1t, Wv1t, Wk2t, Wv2t, Wot);

    // merged Q|K1|V1|K2|V2 projection: 4096 x 7168 x 1024
    gemm_proj<<<dim3(56, 32), blk, 0, stream>>>(Xq, Xkv, Wqt, Qp, K1p, V1t, K2p, V2t);

    attend_mfma<64, 128, true, false, true><<<dim3(32, 32), blk, 0, stream>>>(
        Qp, K1p, V1t, sink, Hb);
    attend_mfma<128, 64, false, true, false><<<dim3(32, 32), blk, 0, stream>>>(
        Hb, K2p, V2t, sink, AO);

    gemm_out<<<dim3(8, 32), blk, 0, stream>>>(AO, Wot, out);
}